// Round 1
// baseline (443.531 us; speedup 1.0000x reference)
//
#include <hip/hip_runtime.h>

#define N_NODES 40000
#define N_EDGES 640000

// ---------------- zero fill ----------------
__global__ void zero_f4(float4* __restrict__ p, int n4) {
    int i = blockIdx.x * blockDim.x + threadIdx.x;
    if (i < n4) p[i] = make_float4(0.f, 0.f, 0.f, 0.f);
}

// ---------------- GEMM: Y[n, DOUT] = X[n,128] @ W[128, DOUT] ----------------
// 16 rows per block staged in LDS (padded), 256 threads, each thread computes
// RPT = 16*DOUT/256 outputs (same col, consecutive rows).
template<int DOUT>
__global__ __launch_bounds__(256) void gemm_rows(const float* __restrict__ X,
                                                 const float* __restrict__ W,
                                                 float* __restrict__ Y) {
    constexpr int K    = 128;
    constexpr int ROWS = 16;
    constexpr int LDK  = K + 4;  // pad to break power-of-2 bank stride
    __shared__ float lds[ROWS * LDK];

    const int row0 = blockIdx.x * ROWS;

    // cooperative load: 16 rows x 32 float4 = 512 float4, 2 per thread
    for (int i = threadIdx.x; i < ROWS * (K / 4); i += 256) {
        int r  = i / (K / 4);
        int c4 = i % (K / 4);
        float4 v = ((const float4*)(X + (size_t)(row0 + r) * K))[c4];
        *(float4*)&lds[r * LDK + c4 * 4] = v;
    }
    __syncthreads();

    constexpr int RPT = ROWS * DOUT / 256;
    const int col = threadIdx.x % DOUT;
    const int rg  = threadIdx.x / DOUT;

    float acc[RPT];
#pragma unroll
    for (int r = 0; r < RPT; r++) acc[r] = 0.f;

    for (int k = 0; k < K; k++) {
        float w = W[k * DOUT + col];
#pragma unroll
        for (int r = 0; r < RPT; r++)
            acc[r] += lds[(rg * RPT + r) * LDK + k] * w;
    }

#pragma unroll
    for (int r = 0; r < RPT; r++)
        Y[(size_t)(row0 + rg * RPT + r) * DOUT + col] = acc[r];
}

// ---------------- scatter: H[dst] += T[src], dst sorted ----------------
// One wave per chunk of edges. Lane owns V = D/64 contiguous floats.
// Accumulate runs of equal dst in registers; flush via atomicAdd at run end.
template<int D>
__global__ __launch_bounds__(256) void scatter_add(const float* __restrict__ T,
                                                   const int* __restrict__ srcE,
                                                   const int* __restrict__ dstE,
                                                   float* __restrict__ H,
                                                   int nEdges, int edgesPerWave) {
    constexpr int V = D / 64;
    const int wave = blockIdx.x * (blockDim.x >> 6) + (threadIdx.x >> 6);
    const int lane = threadIdx.x & 63;
    long e0 = (long)wave * edgesPerWave;
    if (e0 >= nEdges) return;
    long e1 = e0 + edgesPerWave;
    if (e1 > nEdges) e1 = nEdges;

    float acc[V];
#pragma unroll
    for (int v = 0; v < V; v++) acc[v] = 0.f;

    int d = dstE[e0];
    for (long e = e0; e < e1; e++) {
        int s = srcE[e];
        const float* p = T + (size_t)s * D + lane * V;
        if constexpr (V == 2) {
            float2 t = *(const float2*)p;
            acc[0] += t.x;
            acc[1] += t.y;
        } else {
            acc[0] += *p;
        }
        int dn = (e + 1 < e1) ? dstE[e + 1] : -1;
        if (dn != d) {
            float* q = H + (size_t)d * D + lane * V;
#pragma unroll
            for (int v = 0; v < V; v++) atomicAdd(q + v, acc[v]);
#pragma unroll
            for (int v = 0; v < V; v++) acc[v] = 0.f;
            d = dn;
        }
    }
}

extern "C" void kernel_launch(void* const* d_in, const int* in_sizes, int n_in,
                              void* d_out, int out_size, void* d_ws, size_t ws_size,
                              hipStream_t stream) {
    const int*   src  = (const int*)d_in[0];
    const int*   dst  = (const int*)d_in[1];
    const float* feat = (const float*)d_in[2];
    const float* W1   = (const float*)d_in[3];
    const float* W2   = (const float*)d_in[4];
    const float* W3   = (const float*)d_in[5];
    float* out = (float*)d_out;

    float* bufA = (float*)d_ws;                       // t buffer: N x 128
    float* bufB = bufA + (size_t)N_NODES * 128;       // h buffer: N x 128

    const int EPW = 128;                               // edges per wave
    const int nWaves = (N_EDGES + EPW - 1) / EPW;      // 5000
    const int scatterBlocks = (nWaves + 3) / 4;        // 4 waves/block

    const int zero128 = N_NODES * 128 / 4;             // float4 count
    const int zero64  = N_NODES * 64 / 4;

    // ---- Layer 1: t1 = feat @ W1 ; h1 = segsum(t1[src]) ----
    gemm_rows<128><<<N_NODES / 16, 256, 0, stream>>>(feat, W1, bufA);
    zero_f4<<<(zero128 + 255) / 256, 256, 0, stream>>>((float4*)bufB, zero128);
    scatter_add<128><<<scatterBlocks, 256, 0, stream>>>(bufA, src, dst, bufB,
                                                        N_EDGES, EPW);

    // ---- Layer 2: t2 = h1 @ W2 ; h2 = segsum(t2[src]) ----
    gemm_rows<128><<<N_NODES / 16, 256, 0, stream>>>(bufB, W2, bufA);
    zero_f4<<<(zero128 + 255) / 256, 256, 0, stream>>>((float4*)bufB, zero128);
    scatter_add<128><<<scatterBlocks, 256, 0, stream>>>(bufA, src, dst, bufB,
                                                        N_EDGES, EPW);

    // ---- Layer 3: t3 = h2 @ W3 (N x 64) ; out = segsum(t3[src]) ----
    gemm_rows<64><<<N_NODES / 16, 256, 0, stream>>>(bufB, W3, bufA);
    zero_f4<<<(zero64 + 255) / 256, 256, 0, stream>>>((float4*)out, zero64);
    scatter_add<64><<<scatterBlocks, 256, 0, stream>>>(bufA, src, dst, out,
                                                       N_EDGES, EPW);
}

// Round 2
// 301.618 us; speedup vs baseline: 1.4705x; 1.4705x over previous
//
#include <hip/hip_runtime.h>

#define N_NODES 40000
#define N_EDGES 640000

// ---------------- zero fill ----------------
__global__ void zero_f4(float4* __restrict__ p, int n4) {
    int i = blockIdx.x * blockDim.x + threadIdx.x;
    if (i < n4) p[i] = make_float4(0.f, 0.f, 0.f, 0.f);
}

// ---------------- GEMM: Y[n, DOUT] = X[n,128] @ W[128, DOUT] ----------------
// 64x64 block tile, 4x4 per-thread tile, K in slices of 16 staged in LDS
// (X slice stored k-major/transposed so compute reads are ds_read_b128).
template<int DOUT>
__global__ __launch_bounds__(256) void gemm_tile(const float* __restrict__ X,
                                                 const float* __restrict__ W,
                                                 float* __restrict__ Y) {
    constexpr int K  = 128;
    constexpr int KK = 16;
    constexpr int M  = 64;
    constexpr int NT = 64;
    __shared__ float Xs[KK][M + 4];    // transposed: [k][row]
    __shared__ float Ws[KK][NT + 4];   // [k][col]

    const int row0 = blockIdx.x * M;
    const int col0 = blockIdx.y * NT;

    const int tx = threadIdx.x % 16;   // col group (4 cols)
    const int ty = threadIdx.x / 16;   // row group (4 rows)

    // X-stage thread mapping: r = tid/4 (row), kq = tid%4 (k-quad)
    const int xr  = threadIdx.x / 4;
    const int xkq = threadIdx.x % 4;
    // W-stage: k = tid/16, c4 = tid%16
    const int wk  = threadIdx.x / 16;
    const int wc4 = threadIdx.x % 16;

    float acc[4][4];
#pragma unroll
    for (int i = 0; i < 4; i++)
#pragma unroll
        for (int j = 0; j < 4; j++) acc[i][j] = 0.f;

    for (int kb = 0; kb < K; kb += KK) {
        // stage X[row0..row0+63][kb..kb+15] transposed
        float4 xv = *(const float4*)(X + (size_t)(row0 + xr) * K + kb + xkq * 4);
        Xs[xkq * 4 + 0][xr] = xv.x;
        Xs[xkq * 4 + 1][xr] = xv.y;
        Xs[xkq * 4 + 2][xr] = xv.z;
        Xs[xkq * 4 + 3][xr] = xv.w;
        // stage W[kb..kb+15][col0..col0+63]
        *(float4*)&Ws[wk][wc4 * 4] =
            *(const float4*)(W + (size_t)(kb + wk) * DOUT + col0 + wc4 * 4);
        __syncthreads();

#pragma unroll
        for (int k = 0; k < KK; k++) {
            float4 a = *(const float4*)&Xs[k][ty * 4];
            float4 b = *(const float4*)&Ws[k][tx * 4];
            const float av[4] = {a.x, a.y, a.z, a.w};
            const float bv[4] = {b.x, b.y, b.z, b.w};
#pragma unroll
            for (int i = 0; i < 4; i++)
#pragma unroll
                for (int j = 0; j < 4; j++) acc[i][j] += av[i] * bv[j];
        }
        __syncthreads();
    }

#pragma unroll
    for (int i = 0; i < 4; i++) {
        float4 o = make_float4(acc[i][0], acc[i][1], acc[i][2], acc[i][3]);
        *(float4*)(Y + (size_t)(row0 + ty * 4 + i) * DOUT + col0 + tx * 4) = o;
    }
}

// ---------------- scatter: H[dst] += T[src], dst sorted ----------------
// One wave per 32-edge chunk; lane owns V = D/64 contiguous floats.
// Unroll 4 edges: int4 index loads, 4 independent gathers in flight,
// flush-before-add run accumulation (no lookahead needed).
template<int D>
__global__ __launch_bounds__(256) void scatter_add(const float* __restrict__ T,
                                                   const int* __restrict__ srcE,
                                                   const int* __restrict__ dstE,
                                                   float* __restrict__ H,
                                                   int nEdges, int edgesPerWave) {
    constexpr int V = D / 64;
    const int wave = blockIdx.x * (blockDim.x >> 6) + (threadIdx.x >> 6);
    const int lane = threadIdx.x & 63;
    int e0 = wave * edgesPerWave;
    if (e0 >= nEdges) return;
    int e1 = e0 + edgesPerWave;
    if (e1 > nEdges) e1 = nEdges;

    float acc[V];
#pragma unroll
    for (int v = 0; v < V; v++) acc[v] = 0.f;

    int d = dstE[e0];
    for (int e = e0; e < e1; e += 4) {
        int4 s4 = *(const int4*)(srcE + e);
        int4 d4 = *(const int4*)(dstE + e);
        const int ss[4] = {s4.x, s4.y, s4.z, s4.w};
        const int dd[4] = {d4.x, d4.y, d4.z, d4.w};

        float vals[4][V];
#pragma unroll
        for (int j = 0; j < 4; j++) {
            const float* p = T + (size_t)ss[j] * D + lane * V;
            if constexpr (V == 2) {
                float2 t = *(const float2*)p;
                vals[j][0] = t.x;
                vals[j][1] = t.y;
            } else {
                vals[j][0] = *p;
            }
        }

#pragma unroll
        for (int j = 0; j < 4; j++) {
            if (dd[j] != d) {
                float* q = H + (size_t)d * D + lane * V;
#pragma unroll
                for (int v = 0; v < V; v++) atomicAdd(q + v, acc[v]);
#pragma unroll
                for (int v = 0; v < V; v++) acc[v] = 0.f;
                d = dd[j];
            }
#pragma unroll
            for (int v = 0; v < V; v++) acc[v] += vals[j][v];
        }
    }
    float* q = H + (size_t)d * D + lane * V;
#pragma unroll
    for (int v = 0; v < V; v++) atomicAdd(q + v, acc[v]);
}

extern "C" void kernel_launch(void* const* d_in, const int* in_sizes, int n_in,
                              void* d_out, int out_size, void* d_ws, size_t ws_size,
                              hipStream_t stream) {
    const int*   src  = (const int*)d_in[0];
    const int*   dst  = (const int*)d_in[1];
    const float* feat = (const float*)d_in[2];
    const float* W1   = (const float*)d_in[3];
    const float* W2   = (const float*)d_in[4];
    const float* W3   = (const float*)d_in[5];
    float* out = (float*)d_out;

    float* bufA = (float*)d_ws;                       // t buffer: N x 128
    float* bufB = bufA + (size_t)N_NODES * 128;       // h buffer: N x 128

    const int EPW = 32;                                // edges per wave
    const int nWaves = N_EDGES / EPW;                  // 20000
    const int scatterBlocks = (nWaves + 3) / 4;        // 4 waves/block

    const int zero128 = N_NODES * 128 / 4;             // float4 count
    const int zero64  = N_NODES * 64 / 4;

    dim3 g128(N_NODES / 64, 2);                        // 625 x 2 tiles
    dim3 g64(N_NODES / 64, 1);

    // ---- Layer 1: t1 = feat @ W1 ; h1 = segsum(t1[src]) ----
    gemm_tile<128><<<g128, 256, 0, stream>>>(feat, W1, bufA);
    zero_f4<<<(zero128 + 255) / 256, 256, 0, stream>>>((float4*)bufB, zero128);
    scatter_add<128><<<scatterBlocks, 256, 0, stream>>>(bufA, src, dst, bufB,
                                                        N_EDGES, EPW);

    // ---- Layer 2: t2 = h1 @ W2 ; h2 = segsum(t2[src]) ----
    gemm_tile<128><<<g128, 256, 0, stream>>>(bufB, W2, bufA);
    zero_f4<<<(zero128 + 255) / 256, 256, 0, stream>>>((float4*)bufB, zero128);
    scatter_add<128><<<scatterBlocks, 256, 0, stream>>>(bufA, src, dst, bufB,
                                                        N_EDGES, EPW);

    // ---- Layer 3: t3 = h2 @ W3 (N x 64) ; out = segsum(t3[src]) ----
    gemm_tile<64><<<g64, 256, 0, stream>>>(bufB, W3, bufA);
    zero_f4<<<(zero64 + 255) / 256, 256, 0, stream>>>((float4*)out, zero64);
    scatter_add<64><<<scatterBlocks, 256, 0, stream>>>(bufA, src, dst, out,
                                                       N_EDGES, EPW);
}

// Round 3
// 224.802 us; speedup vs baseline: 1.9730x; 1.3417x over previous
//
#include <hip/hip_runtime.h>
#include <hip/hip_bf16.h>

#define N_NODES 40000
#define N_EDGES 640000

struct alignas(8) bf16x4 { __hip_bfloat16 v[4]; };

// ---------------- CSR row pointer: rowptr[n] = lower_bound(dst, n) ----------------
__global__ void build_rowptr(const int* __restrict__ dst, int* __restrict__ rowptr) {
    int n = blockIdx.x * blockDim.x + threadIdx.x;
    if (n > N_NODES) return;
    int lo = 0, hi = N_EDGES;
    while (lo < hi) {
        int mid = (lo + hi) >> 1;
        if (dst[mid] < n) lo = mid + 1; else hi = mid;
    }
    rowptr[n] = lo;
}

// ---------------- GEMM: Y[n, DOUT] = X[n,128] @ W[128, DOUT] ----------------
// 64x64 block tile, 4x4 per-thread tile, K slices of 16 in LDS (X transposed).
// OUT_BF16 selects bf16 vs fp32 output.
template<int DOUT, bool OUT_BF16>
__global__ __launch_bounds__(256) void gemm_tile(const float* __restrict__ X,
                                                 const float* __restrict__ W,
                                                 void* __restrict__ Yv) {
    constexpr int K  = 128;
    constexpr int KK = 16;
    constexpr int M  = 64;
    constexpr int NT = 64;
    __shared__ float Xs[KK][M + 4];    // transposed: [k][row]
    __shared__ float Ws[KK][NT + 4];   // [k][col]

    const int row0 = blockIdx.x * M;
    const int col0 = blockIdx.y * NT;

    const int tx = threadIdx.x % 16;   // col group (4 cols)
    const int ty = threadIdx.x / 16;   // row group (4 rows)

    const int xr  = threadIdx.x / 4;   // X-stage row
    const int xkq = threadIdx.x % 4;   // X-stage k-quad
    const int wk  = threadIdx.x / 16;  // W-stage k
    const int wc4 = threadIdx.x % 16;  // W-stage col-quad

    float acc[4][4];
#pragma unroll
    for (int i = 0; i < 4; i++)
#pragma unroll
        for (int j = 0; j < 4; j++) acc[i][j] = 0.f;

    for (int kb = 0; kb < K; kb += KK) {
        float4 xv = *(const float4*)(X + (size_t)(row0 + xr) * K + kb + xkq * 4);
        Xs[xkq * 4 + 0][xr] = xv.x;
        Xs[xkq * 4 + 1][xr] = xv.y;
        Xs[xkq * 4 + 2][xr] = xv.z;
        Xs[xkq * 4 + 3][xr] = xv.w;
        *(float4*)&Ws[wk][wc4 * 4] =
            *(const float4*)(W + (size_t)(kb + wk) * DOUT + col0 + wc4 * 4);
        __syncthreads();

#pragma unroll
        for (int k = 0; k < KK; k++) {
            float4 a = *(const float4*)&Xs[k][ty * 4];
            float4 b = *(const float4*)&Ws[k][tx * 4];
            const float av[4] = {a.x, a.y, a.z, a.w};
            const float bv[4] = {b.x, b.y, b.z, b.w};
#pragma unroll
            for (int i = 0; i < 4; i++)
#pragma unroll
                for (int j = 0; j < 4; j++) acc[i][j] += av[i] * bv[j];
        }
        __syncthreads();
    }

#pragma unroll
    for (int i = 0; i < 4; i++) {
        const size_t off = (size_t)(row0 + ty * 4 + i) * DOUT + col0 + tx * 4;
        if constexpr (OUT_BF16) {
            bf16x4 o;
#pragma unroll
            for (int j = 0; j < 4; j++) o.v[j] = __float2bfloat16(acc[i][j]);
            *(bf16x4*)((__hip_bfloat16*)Yv + off) = o;
        } else {
            *(float4*)((float*)Yv + off) =
                make_float4(acc[i][0], acc[i][1], acc[i][2], acc[i][3]);
        }
    }
}

// ---------------- CSR scatter, D=128, bf16 in, fp32 out ----------------
// One wave per node; lane owns 2 columns (bf16x2 load = 4B/lane, 256B/wave/edge).
__global__ __launch_bounds__(256) void scatter_csr_bf16_128(
        const __hip_bfloat162* __restrict__ T, const int* __restrict__ srcE,
        const int* __restrict__ rowptr, float* __restrict__ H) {
    const int node = blockIdx.x * (blockDim.x >> 6) + (threadIdx.x >> 6);
    if (node >= N_NODES) return;
    const int lane = threadIdx.x & 63;
    const int e0 = rowptr[node], e1 = rowptr[node + 1];

    float ax = 0.f, ay = 0.f;
    int e = e0;
    for (; e + 4 <= e1; e += 4) {
        int s0 = srcE[e + 0], s1 = srcE[e + 1], s2 = srcE[e + 2], s3 = srcE[e + 3];
        __hip_bfloat162 t0 = T[(size_t)s0 * 64 + lane];
        __hip_bfloat162 t1 = T[(size_t)s1 * 64 + lane];
        __hip_bfloat162 t2 = T[(size_t)s2 * 64 + lane];
        __hip_bfloat162 t3 = T[(size_t)s3 * 64 + lane];
        ax += __bfloat162float(t0.x) + __bfloat162float(t1.x)
            + __bfloat162float(t2.x) + __bfloat162float(t3.x);
        ay += __bfloat162float(t0.y) + __bfloat162float(t1.y)
            + __bfloat162float(t2.y) + __bfloat162float(t3.y);
    }
    for (; e < e1; e++) {
        __hip_bfloat162 t = T[(size_t)srcE[e] * 64 + lane];
        ax += __bfloat162float(t.x);
        ay += __bfloat162float(t.y);
    }
    *(float2*)(H + (size_t)node * 128 + lane * 2) = make_float2(ax, ay);
}

// ---------------- CSR scatter, D=64, fp32 in, fp32 out ----------------
// One wave per node; lane owns 1 column (4B/lane, 256B/wave/edge).
__global__ __launch_bounds__(256) void scatter_csr_f32_64(
        const float* __restrict__ T, const int* __restrict__ srcE,
        const int* __restrict__ rowptr, float* __restrict__ H) {
    const int node = blockIdx.x * (blockDim.x >> 6) + (threadIdx.x >> 6);
    if (node >= N_NODES) return;
    const int lane = threadIdx.x & 63;
    const int e0 = rowptr[node], e1 = rowptr[node + 1];

    float acc = 0.f;
    int e = e0;
    for (; e + 4 <= e1; e += 4) {
        int s0 = srcE[e + 0], s1 = srcE[e + 1], s2 = srcE[e + 2], s3 = srcE[e + 3];
        acc += T[(size_t)s0 * 64 + lane] + T[(size_t)s1 * 64 + lane]
             + T[(size_t)s2 * 64 + lane] + T[(size_t)s3 * 64 + lane];
    }
    for (; e < e1; e++) acc += T[(size_t)srcE[e] * 64 + lane];
    H[(size_t)node * 64 + lane] = acc;
}

extern "C" void kernel_launch(void* const* d_in, const int* in_sizes, int n_in,
                              void* d_out, int out_size, void* d_ws, size_t ws_size,
                              hipStream_t stream) {
    const int*   src  = (const int*)d_in[0];
    const int*   dst  = (const int*)d_in[1];
    const float* feat = (const float*)d_in[2];
    const float* W1   = (const float*)d_in[3];
    const float* W2   = (const float*)d_in[4];
    const float* W3   = (const float*)d_in[5];
    float* out = (float*)d_out;

    // ws layout (bytes):
    //   [0, 10.24M)      bufT : N x 128 bf16  (also reused as N x 64 fp32 for layer 3)
    //   [10.24M, +160K)  rowptr : (N+1) ints
    //   [20.48M, 40.96M) bufH : N x 128 fp32
    char* wsb = (char*)d_ws;
    __hip_bfloat16* bufT = (__hip_bfloat16*)wsb;
    int*   rowptr = (int*)(wsb + (size_t)N_NODES * 128 * 2);
    float* bufH   = (float*)(wsb + (size_t)N_NODES * 128 * 4);
    float* bufT3  = (float*)wsb;

    dim3 g128(N_NODES / 64, 2);
    dim3 g64(N_NODES / 64, 1);
    const int scatterBlocks = (N_NODES + 3) / 4;   // 4 waves (nodes) per block

    build_rowptr<<<(N_NODES + 256) / 256, 256, 0, stream>>>(dst, rowptr);

    // ---- Layer 1: t1 = feat @ W1 (bf16) ; h1 = segsum(t1[src]) ----
    gemm_tile<128, true><<<g128, 256, 0, stream>>>(feat, W1, bufT);
    scatter_csr_bf16_128<<<scatterBlocks, 256, 0, stream>>>(
        (const __hip_bfloat162*)bufT, src, rowptr, bufH);

    // ---- Layer 2: t2 = h1 @ W2 (bf16) ; h2 = segsum(t2[src]) ----
    gemm_tile<128, true><<<g128, 256, 0, stream>>>(bufH, W2, bufT);
    scatter_csr_bf16_128<<<scatterBlocks, 256, 0, stream>>>(
        (const __hip_bfloat162*)bufT, src, rowptr, bufH);

    // ---- Layer 3: t3 = h2 @ W3 (fp32, Nx64) ; out = segsum(t3[src]) ----
    gemm_tile<64, false><<<g64, 256, 0, stream>>>(bufH, W3, bufT3);
    scatter_csr_f32_64<<<scatterBlocks, 256, 0, stream>>>(bufT3, src, rowptr, out);
}

// Round 4
// 205.249 us; speedup vs baseline: 2.1609x; 1.0953x over previous
//
#include <hip/hip_runtime.h>
#include <hip/hip_bf16.h>

#define N_NODES 40000
#define N_EDGES 640000

typedef __attribute__((ext_vector_type(8))) short bfrag;   // 8 bf16
typedef __attribute__((ext_vector_type(4))) float ffrag;   // 4 fp32 acc

__device__ __forceinline__ float b2f(unsigned short u) {
    unsigned int x = ((unsigned int)u) << 16;
    return __builtin_bit_cast(float, x);
}
__device__ __forceinline__ unsigned short f2b(float f) {
    return __builtin_bit_cast(unsigned short, __float2bfloat16(f));
}

// ---------------- prep: rowptr binary search + W transpose/convert ----------------
// blocks [0,157): rowptr[n] = lower_bound(dst, n).  blocks [157,317): Wt bf16.
__global__ __launch_bounds__(256) void prep(const int* __restrict__ dst,
                                            int* __restrict__ rowptr,
                                            const float* __restrict__ W1,
                                            const float* __restrict__ W2,
                                            const float* __restrict__ W3,
                                            unsigned short* __restrict__ Wt1,
                                            unsigned short* __restrict__ Wt2,
                                            unsigned short* __restrict__ Wt3) {
    int bid = blockIdx.x;
    if (bid < 157) {
        int n = bid * 256 + threadIdx.x;
        if (n > N_NODES) return;
        int lo = 0, hi = N_EDGES;
        while (lo < hi) {
            int mid = (lo + hi) >> 1;
            if (dst[mid] < n) lo = mid + 1; else hi = mid;
        }
        rowptr[n] = lo;
    } else {
        int i = (bid - 157) * 256 + threadIdx.x;   // 0..40959
        if (i < 16384) {
            int n = i & 127, k = i >> 7;
            Wt1[n * 128 + k] = f2b(W1[k * 128 + n]);
        } else if (i < 32768) {
            int j = i - 16384;
            int n = j & 127, k = j >> 7;
            Wt2[n * 128 + k] = f2b(W2[k * 128 + n]);
        } else {
            int j = i - 32768;
            int n = j & 63, k = j >> 6;
            Wt3[n * 128 + k] = f2b(W3[k * 64 + n]);
        }
    }
}

// ---------------- MFMA GEMM: Y[N, DOUT] = X[N,128] @ W[128,DOUT] ----------------
// A and B(=W^T) fragments loaded directly from global (16B contiguous per lane,
// A[m=lane&15][k=quad*8+j]); no LDS. Block = 64 rows, 4 waves.
// DOUT=128: wave w -> rows (w>>1)*32, cols (w&1)*64 (RF=2, CF=4)
// DOUT=64 : wave w -> rows w*16, cols 0..64        (RF=1, CF=4)
template<int DOUT, bool A_FP32, bool OUT_BF16>
__global__ __launch_bounds__(256) void gemm_mfma(const void* __restrict__ Xv,
                                                 const unsigned short* __restrict__ Wt,
                                                 void* __restrict__ Yv) {
    constexpr int RF = (DOUT == 128) ? 2 : 1;
    constexpr int CF = 4;
    const int w    = threadIdx.x >> 6;
    const int lane = threadIdx.x & 63;
    const int ml   = lane & 15;
    const int quad = lane >> 4;

    const int row0 = blockIdx.x * 64 + ((DOUT == 128) ? (w >> 1) * 32 : w * 16);
    const int col0 = (DOUT == 128) ? (w & 1) * 64 : 0;

    ffrag acc[RF][CF];
#pragma unroll
    for (int r = 0; r < RF; r++)
#pragma unroll
        for (int c = 0; c < CF; c++) acc[r][c] = (ffrag)0.f;

#pragma unroll
    for (int kb = 0; kb < 128; kb += 32) {
        bfrag a[RF];
#pragma unroll
        for (int r = 0; r < RF; r++) {
            const int row = row0 + r * 16 + ml;
            if constexpr (A_FP32) {
                const float* p = (const float*)Xv + (size_t)row * 128 + kb + quad * 8;
                float4 u0 = *(const float4*)p;
                float4 u1 = *(const float4*)(p + 4);
                bfrag t;
                t[0] = (short)f2b(u0.x); t[1] = (short)f2b(u0.y);
                t[2] = (short)f2b(u0.z); t[3] = (short)f2b(u0.w);
                t[4] = (short)f2b(u1.x); t[5] = (short)f2b(u1.y);
                t[6] = (short)f2b(u1.z); t[7] = (short)f2b(u1.w);
                a[r] = t;
            } else {
                a[r] = *(const bfrag*)((const unsigned short*)Xv +
                                       (size_t)row * 128 + kb + quad * 8);
            }
        }
#pragma unroll
        for (int c = 0; c < CF; c++) {
            const int n = col0 + c * 16 + ml;
            bfrag b = *(const bfrag*)(Wt + (size_t)n * 128 + kb + quad * 8);
#pragma unroll
            for (int r = 0; r < RF; r++)
                acc[r][c] = __builtin_amdgcn_mfma_f32_16x16x32_bf16(a[r], b,
                                                                    acc[r][c], 0, 0, 0);
        }
    }

    // D mapping: row = quad*4 + reg, col = lane&15
#pragma unroll
    for (int r = 0; r < RF; r++)
#pragma unroll
        for (int c = 0; c < CF; c++)
#pragma unroll
            for (int i = 0; i < 4; i++) {
                const int row = row0 + r * 16 + quad * 4 + i;
                const int col = col0 + c * 16 + ml;
                if constexpr (OUT_BF16)
                    ((unsigned short*)Yv)[(size_t)row * DOUT + col] = f2b(acc[r][c][i]);
                else
                    ((float*)Yv)[(size_t)row * DOUT + col] = acc[r][c][i];
            }
}

// ---------------- CSR scatter, D=128, bf16 in, bf16 out ----------------
// One wave per node; half-waves take alternate edges; lane owns 4 cols (8B loads).
__global__ __launch_bounds__(256) void scatter_bf16_128(
        const unsigned short* __restrict__ T, const int* __restrict__ srcE,
        const int* __restrict__ rowptr, unsigned short* __restrict__ H) {
    const int node = blockIdx.x * 4 + (threadIdx.x >> 6);
    if (node >= N_NODES) return;
    const int lane = threadIdx.x & 63;
    const int sub  = lane >> 5;
    const int c    = lane & 31;          // cols c*4 .. c*4+3
    const int e0 = rowptr[node], e1 = rowptr[node + 1];

    float a0 = 0.f, a1 = 0.f, a2 = 0.f, a3 = 0.f;
    int e = e0;
    for (; e + 8 <= e1; e += 8) {
        int sA = srcE[e + 0 + sub];
        int sB = srcE[e + 2 + sub];
        int sC = srcE[e + 4 + sub];
        int sD = srcE[e + 6 + sub];
        ushort4 tA = *(const ushort4*)(T + (size_t)sA * 128 + c * 4);
        ushort4 tB = *(const ushort4*)(T + (size_t)sB * 128 + c * 4);
        ushort4 tC = *(const ushort4*)(T + (size_t)sC * 128 + c * 4);
        ushort4 tD = *(const ushort4*)(T + (size_t)sD * 128 + c * 4);
        a0 += b2f(tA.x) + b2f(tB.x) + b2f(tC.x) + b2f(tD.x);
        a1 += b2f(tA.y) + b2f(tB.y) + b2f(tC.y) + b2f(tD.y);
        a2 += b2f(tA.z) + b2f(tB.z) + b2f(tC.z) + b2f(tD.z);
        a3 += b2f(tA.w) + b2f(tB.w) + b2f(tC.w) + b2f(tD.w);
    }
    for (; e < e1; e += 2) {
        int edge = e + sub;
        if (edge < e1) {
            int s = srcE[edge];
            ushort4 t = *(const ushort4*)(T + (size_t)s * 128 + c * 4);
            a0 += b2f(t.x); a1 += b2f(t.y); a2 += b2f(t.z); a3 += b2f(t.w);
        }
    }
    a0 += __shfl_xor(a0, 32);
    a1 += __shfl_xor(a1, 32);
    a2 += __shfl_xor(a2, 32);
    a3 += __shfl_xor(a3, 32);
    if (sub == 0) {
        ushort4 o;
        o.x = f2b(a0); o.y = f2b(a1); o.z = f2b(a2); o.w = f2b(a3);
        *(ushort4*)(H + (size_t)node * 128 + c * 4) = o;
    }
}

// ---------------- CSR scatter, D=64, fp32 in, fp32 out ----------------
// Half-waves take alternate edges; lane owns 2 cols (float2, 8B loads).
__global__ __launch_bounds__(256) void scatter_f32_64(
        const float* __restrict__ T, const int* __restrict__ srcE,
        const int* __restrict__ rowptr, float* __restrict__ H) {
    const int node = blockIdx.x * 4 + (threadIdx.x >> 6);
    if (node >= N_NODES) return;
    const int lane = threadIdx.x & 63;
    const int sub  = lane >> 5;
    const int c    = lane & 31;          // cols c*2, c*2+1
    const int e0 = rowptr[node], e1 = rowptr[node + 1];

    float ax = 0.f, ay = 0.f;
    int e = e0;
    for (; e + 8 <= e1; e += 8) {
        int sA = srcE[e + 0 + sub];
        int sB = srcE[e + 2 + sub];
        int sC = srcE[e + 4 + sub];
        int sD = srcE[e + 6 + sub];
        float2 tA = *(const float2*)(T + (size_t)sA * 64 + c * 2);
        float2 tB = *(const float2*)(T + (size_t)sB * 64 + c * 2);
        float2 tC = *(const float2*)(T + (size_t)sC * 64 + c * 2);
        float2 tD = *(const float2*)(T + (size_t)sD * 64 + c * 2);
        ax += tA.x + tB.x + tC.x + tD.x;
        ay += tA.y + tB.y + tC.y + tD.y;
    }
    for (; e < e1; e += 2) {
        int edge = e + sub;
        if (edge < e1) {
            int s = srcE[edge];
            float2 t = *(const float2*)(T + (size_t)s * 64 + c * 2);
            ax += t.x; ay += t.y;
        }
    }
    ax += __shfl_xor(ax, 32);
    ay += __shfl_xor(ay, 32);
    if (sub == 0)
        *(float2*)(H + (size_t)node * 64 + c * 2) = make_float2(ax, ay);
}

extern "C" void kernel_launch(void* const* d_in, const int* in_sizes, int n_in,
                              void* d_out, int out_size, void* d_ws, size_t ws_size,
                              hipStream_t stream) {
    const int*   src  = (const int*)d_in[0];
    const int*   dst  = (const int*)d_in[1];
    const float* feat = (const float*)d_in[2];
    const float* W1   = (const float*)d_in[3];
    const float* W2   = (const float*)d_in[4];
    const float* W3   = (const float*)d_in[5];
    float* out = (float*)d_out;

    // ws layout (bytes):
    //   [0, 10.24M)        T  : N x 128 bf16   (reused as T3: N x 64 fp32)
    //   [10.24M, 20.48M)   H  : N x 128 bf16
    //   [20.48M, +160K)    rowptr
    //   [+..]              Wt1 (32KB), Wt2 (32KB), Wt3 (16KB) bf16 transposed
    char* wsb = (char*)d_ws;
    unsigned short* T  = (unsigned short*)wsb;
    unsigned short* H  = (unsigned short*)(wsb + (size_t)10485760);
    int* rowptr        = (int*)(wsb + (size_t)20971520);
    unsigned short* Wt1 = (unsigned short*)(wsb + (size_t)20971520 + 163840);
    unsigned short* Wt2 = Wt1 + 16384;
    unsigned short* Wt3 = Wt2 + 16384;
    float* T3 = (float*)wsb;

    const int scatterBlocks = (N_NODES + 3) / 4;   // 10000

    prep<<<317, 256, 0, stream>>>(dst, rowptr, W1, W2, W3, Wt1, Wt2, Wt3);

    // ---- Layer 1: T1 = bf16(feat @ W1) ; h1 = bf16(segsum(T1[src])) ----
    gemm_mfma<128, true, true><<<625, 256, 0, stream>>>(feat, Wt1, T);
    scatter_bf16_128<<<scatterBlocks, 256, 0, stream>>>(T, src, rowptr, H);

    // ---- Layer 2: T2 = bf16(h1 @ W2) ; h2 = bf16(segsum(T2[src])) ----
    gemm_mfma<128, false, true><<<625, 256, 0, stream>>>(H, Wt2, T);
    scatter_bf16_128<<<scatterBlocks, 256, 0, stream>>>(T, src, rowptr, H);

    // ---- Layer 3: T3 = fp32(h2 @ W3) ; out = segsum(T3[src]) ----
    gemm_mfma<64, false, false><<<625, 256, 0, stream>>>(H, Wt3, T3);
    scatter_f32_64<<<scatterBlocks, 256, 0, stream>>>(T3, src, rowptr, out);
}

// Round 5
// 185.025 us; speedup vs baseline: 2.3971x; 1.1093x over previous
//
#include <hip/hip_runtime.h>
#include <hip/hip_bf16.h>

#define N_NODES 40000
#define N_EDGES 640000

typedef __attribute__((ext_vector_type(8))) short bfrag;   // 8 bf16
typedef __attribute__((ext_vector_type(4))) float ffrag;   // 4 fp32 acc

__device__ __forceinline__ float b2f(unsigned short u) {
    unsigned int x = ((unsigned int)u) << 16;
    return __builtin_bit_cast(float, x);
}
__device__ __forceinline__ unsigned short f2b(float f) {
    return __builtin_bit_cast(unsigned short, __float2bfloat16(f));
}

// ---------------- prepA: rowptr binary search + W23 = W2 @ W3 (fp32) ----------------
// blocks [0,157): rowptr[n] = lower_bound(dst, n). blocks [157,161): W23 (128x64).
__global__ __launch_bounds__(256) void prepA(const int* __restrict__ dst,
                                             int* __restrict__ rowptr,
                                             const float* __restrict__ W2,
                                             const float* __restrict__ W3,
                                             float* __restrict__ W23) {
    int bid = blockIdx.x;
    if (bid < 157) {
        int n = bid * 256 + threadIdx.x;
        if (n > N_NODES) return;
        int lo = 0, hi = N_EDGES;
        while (lo < hi) {
            int mid = (lo + hi) >> 1;
            if (dst[mid] < n) lo = mid + 1; else hi = mid;
        }
        rowptr[n] = lo;
    } else {
        int t = (bid - 157) * 256 + threadIdx.x;   // 0..1023
        int k  = t >> 3;                            // 0..127
        int n0 = (t & 7) * 8;                       // 0..56
        float acc[8];
#pragma unroll
        for (int r = 0; r < 8; r++) acc[r] = 0.f;
        for (int j = 0; j < 128; j++) {
            float w2 = W2[k * 128 + j];
#pragma unroll
            for (int r = 0; r < 8; r++) acc[r] += w2 * W3[j * 64 + n0 + r];
        }
#pragma unroll
        for (int r = 0; r < 8; r++) W23[k * 64 + n0 + r] = acc[r];
    }
}

// ---------------- prepB: Wt123[n][k] = bf16( (W1 @ W23)[k][n] ) ----------------
// 4 blocks x 256 threads; thread -> n = t>>4, k0 = (t&15)*8.
__global__ __launch_bounds__(256) void prepB(const float* __restrict__ W1,
                                             const float* __restrict__ W23,
                                             unsigned short* __restrict__ Wt123) {
    int t  = blockIdx.x * 256 + threadIdx.x;   // 0..1023
    int n  = t >> 4;                            // 0..63
    int k0 = (t & 15) * 8;                      // 0..120
    float acc[8];
#pragma unroll
    for (int r = 0; r < 8; r++) acc[r] = 0.f;
    for (int j = 0; j < 128; j++) {
        float w23 = W23[j * 64 + n];
#pragma unroll
        for (int r = 0; r < 8; r++) acc[r] += W1[(k0 + r) * 128 + j] * w23;
    }
#pragma unroll
    for (int r = 0; r < 8; r++) Wt123[n * 128 + k0 + r] = f2b(acc[r]);
}

// ---------------- MFMA GEMM: T[N,64] = bf16( X[N,128] @ W123 ) ----------------
// A fragments converted from fp32 X on the fly; B = Wt123 (transposed bf16),
// both loaded straight from global (16B contiguous per lane). Block = 64 rows.
__global__ __launch_bounds__(256) void gemm_mfma64(const float* __restrict__ X,
                                                   const unsigned short* __restrict__ Wt,
                                                   unsigned short* __restrict__ Y) {
    const int w    = threadIdx.x >> 6;
    const int lane = threadIdx.x & 63;
    const int ml   = lane & 15;
    const int quad = lane >> 4;
    const int row0 = blockIdx.x * 64 + w * 16;

    ffrag acc[4];
#pragma unroll
    for (int c = 0; c < 4; c++) acc[c] = (ffrag)0.f;

#pragma unroll
    for (int kb = 0; kb < 128; kb += 32) {
        const float* p = X + (size_t)(row0 + ml) * 128 + kb + quad * 8;
        float4 u0 = *(const float4*)p;
        float4 u1 = *(const float4*)(p + 4);
        bfrag a;
        a[0] = (short)f2b(u0.x); a[1] = (short)f2b(u0.y);
        a[2] = (short)f2b(u0.z); a[3] = (short)f2b(u0.w);
        a[4] = (short)f2b(u1.x); a[5] = (short)f2b(u1.y);
        a[6] = (short)f2b(u1.z); a[7] = (short)f2b(u1.w);
#pragma unroll
        for (int c = 0; c < 4; c++) {
            const int n = c * 16 + ml;
            bfrag b = *(const bfrag*)(Wt + (size_t)n * 128 + kb + quad * 8);
            acc[c] = __builtin_amdgcn_mfma_f32_16x16x32_bf16(a, b, acc[c], 0, 0, 0);
        }
    }

    // D mapping: row = quad*4 + i, col = lane&15
#pragma unroll
    for (int c = 0; c < 4; c++)
#pragma unroll
        for (int i = 0; i < 4; i++) {
            const int row = row0 + quad * 4 + i;
            const int col = c * 16 + ml;
            Y[(size_t)row * 64 + col] = f2b(acc[c][i]);
        }
}

// ---------------- CSR scatter, D=64, bf16 in ----------------
// One wave per node; 4 sub-groups of 16 lanes take interleaved edges;
// lane owns 4 cols (ushort4 = 8B loads). OUT_F32 selects fp32 vs bf16 store.
template<bool OUT_F32>
__global__ __launch_bounds__(256) void scatter64(const unsigned short* __restrict__ T,
                                                 const int* __restrict__ srcE,
                                                 const int* __restrict__ rowptr,
                                                 void* __restrict__ Hv) {
    const int node = blockIdx.x * 4 + (threadIdx.x >> 6);
    if (node >= N_NODES) return;
    const int lane = threadIdx.x & 63;
    const int sub  = lane >> 4;          // 0..3
    const int c4   = (lane & 15) * 4;    // cols c4..c4+3
    const int e0 = rowptr[node], e1 = rowptr[node + 1];

    float a0 = 0.f, a1 = 0.f, a2 = 0.f, a3 = 0.f;
    int e = e0;
    for (; e + 16 <= e1; e += 16) {
        int sA = srcE[e + 0  + sub];
        int sB = srcE[e + 4  + sub];
        int sC = srcE[e + 8  + sub];
        int sD = srcE[e + 12 + sub];
        ushort4 tA = *(const ushort4*)(T + (size_t)sA * 64 + c4);
        ushort4 tB = *(const ushort4*)(T + (size_t)sB * 64 + c4);
        ushort4 tC = *(const ushort4*)(T + (size_t)sC * 64 + c4);
        ushort4 tD = *(const ushort4*)(T + (size_t)sD * 64 + c4);
        a0 += b2f(tA.x) + b2f(tB.x) + b2f(tC.x) + b2f(tD.x);
        a1 += b2f(tA.y) + b2f(tB.y) + b2f(tC.y) + b2f(tD.y);
        a2 += b2f(tA.z) + b2f(tB.z) + b2f(tC.z) + b2f(tD.z);
        a3 += b2f(tA.w) + b2f(tB.w) + b2f(tC.w) + b2f(tD.w);
    }
    for (; e + 4 <= e1; e += 4) {
        int s = srcE[e + sub];
        ushort4 t = *(const ushort4*)(T + (size_t)s * 64 + c4);
        a0 += b2f(t.x); a1 += b2f(t.y); a2 += b2f(t.z); a3 += b2f(t.w);
    }
    if (e + sub < e1) {
        int s = srcE[e + sub];
        ushort4 t = *(const ushort4*)(T + (size_t)s * 64 + c4);
        a0 += b2f(t.x); a1 += b2f(t.y); a2 += b2f(t.z); a3 += b2f(t.w);
    }

    a0 += __shfl_xor(a0, 16); a0 += __shfl_xor(a0, 32);
    a1 += __shfl_xor(a1, 16); a1 += __shfl_xor(a1, 32);
    a2 += __shfl_xor(a2, 16); a2 += __shfl_xor(a2, 32);
    a3 += __shfl_xor(a3, 16); a3 += __shfl_xor(a3, 32);

    if (sub == 0) {
        if constexpr (OUT_F32) {
            *(float4*)((float*)Hv + (size_t)node * 64 + c4) =
                make_float4(a0, a1, a2, a3);
        } else {
            ushort4 o;
            o.x = f2b(a0); o.y = f2b(a1); o.z = f2b(a2); o.w = f2b(a3);
            *(ushort4*)((unsigned short*)Hv + (size_t)node * 64 + c4) = o;
        }
    }
}

extern "C" void kernel_launch(void* const* d_in, const int* in_sizes, int n_in,
                              void* d_out, int out_size, void* d_ws, size_t ws_size,
                              hipStream_t stream) {
    const int*   src  = (const int*)d_in[0];
    const int*   dst  = (const int*)d_in[1];
    const float* feat = (const float*)d_in[2];
    const float* W1   = (const float*)d_in[3];
    const float* W2   = (const float*)d_in[4];
    const float* W3   = (const float*)d_in[5];
    float* out = (float*)d_out;

    // ws layout (bytes):
    //   [0,       5.12M)   T : N x 64 bf16
    //   [5.25M,  10.37M)   H : N x 64 bf16
    //   [10.5M,  +160K+4)  rowptr (N+1 ints)
    //   [+..]              W23 (128x64 fp32, 32KB), Wt123 (64x128 bf16, 16KB)
    char* wsb = (char*)d_ws;
    unsigned short* T = (unsigned short*)wsb;
    unsigned short* H = (unsigned short*)(wsb + (size_t)5505024);   // 5.25 MB
    int* rowptr       = (int*)(wsb + (size_t)11010048);             // 10.5 MB
    float* W23        = (float*)(wsb + (size_t)11010048 + 163844);
    unsigned short* Wt123 = (unsigned short*)((char*)W23 + 32768);

    const int scatterBlocks = (N_NODES + 3) / 4;   // 10000

    // out = S^3 . (X @ (W1 W2 W3))   (S = segment-sum; W and S commute, no nonlinearity)
    prepA<<<161, 256, 0, stream>>>(dst, rowptr, W2, W3, W23);
    prepB<<<4, 256, 0, stream>>>(W1, W23, Wt123);

    gemm_mfma64<<<625, 256, 0, stream>>>(feat, Wt123, T);

    scatter64<false><<<scatterBlocks, 256, 0, stream>>>(T, src, rowptr, H);
    scatter64<false><<<scatterBlocks, 256, 0, stream>>>(H, src, rowptr, T);
    scatter64<true><<<scatterBlocks, 256, 0, stream>>>(T, src, rowptr, out);
}